// Round 18
// baseline (230.257 us; speedup 1.0000x reference)
//
#include <hip/hip_runtime.h>

typedef float v2f __attribute__((ext_vector_type(2)));

// Async global->LDS, 16B per lane. Dest = wave-uniform base + lane*16.
__device__ __forceinline__ void gload_lds16(const float* g, float* l) {
  __builtin_amdgcn_global_load_lds(
      (const __attribute__((address_space(1))) unsigned int*)g,
      (__attribute__((address_space(3))) unsigned int*)l, 16, 0, 0);
}

// ---------------- K1: sim + dual softmax + heatmap + per-wave argmax ----------------
// R17 champion (219.7 us) with ONE change: the unrolled K-loop iterates
// ca = c8 ^ ea, so the A ds_read offset is a compile-time literal (folds into
// the instruction offset imm) and the B offset needs a single XOR with
// eab = ea ^ eb. Removes ~2/3 of inner-loop address VALU. Per-thread c8
// summation ORDER changes (few-ulp class, same as prior passed reorders).
__global__ __launch_bounds__(256, 4) void fm_main_kernel(
    const float* __restrict__ feat0, const float* __restrict__ feat1,
    float* __restrict__ out, unsigned int* __restrict__ ws, int M)
{
  const int t    = threadIdx.x;
  const int lane = t & 63;
  const int wave = t >> 6;

  __shared__ __align__(16) float sA[4096];      // [2][64][32] halves of cls_f0
  __shared__ __align__(16) float sB[4096];      // [2][64][32] halves of cls_f1 inner
  __shared__ __align__(16) float colps[4][64];  // per-wave col-sum partials

  const int m = blockIdx.x;
  const float* f0m = feat0 + (size_t)m * 8192;   // 64*128
  const float* f1m = feat1 + (size_t)m * 12800;  // 100*128

  // ---- stage: 8 gload_lds per wave, h0 (c<32) first, then h1 ----
  const int pr = lane >> 3;   // row within 8-row chunk
  const int q  = lane & 7;    // slot quad within half
#pragma unroll
  for (int h = 0; h < 2; ++h) {
#pragma unroll
    for (int k = 0; k < 2; ++k) {
      const int p0 = wave * 16 + k * 8;
      const int p  = p0 + pr;
      const int gq = q ^ ((p >> 2) & 7);          // source-side swizzle
      gload_lds16(f0m + p * 128 + h * 32 + gq * 4, &sA[h * 2048 + p0 * 32]);
      const int r = ((p >> 3) + 1) * 10 + (p & 7) + 1;  // inner 8x8 of 10x10
      gload_lds16(f1m + r * 128 + h * 32 + gq * 4, &sB[h * 2048 + p0 * 32]);
    }
  }

  // address setup under the load shadow
  const int st = t & 15, lt = t >> 4;
  const int s4 = st << 2, l4 = lt << 2;
  const int ea  = lt & 7, eb = st & 7;  // read-side XOR (= e(p) of owned rows)
  const int eab = ea ^ eb;
  const float* sAr0 = &sA[l4 * 32];            // A row base, h0
  const float* sAr1 = &sA[2048 + l4 * 32];     // A row base, h1

  v2f acc2[4][4];
#pragma unroll
  for (int i = 0; i < 4; ++i)
#pragma unroll
    for (int j = 0; j < 4; ++j) acc2[i][j] = (v2f){0.0f, 0.0f};

  // ---- h0 ready (oldest 4 loads), all waves -> compute c<32 while h1 drains ----
  asm volatile("s_waitcnt vmcnt(4)" ::: "memory");
  __builtin_amdgcn_s_barrier();
  asm volatile("" ::: "memory");

#pragma unroll
  for (int ca = 0; ca < 8; ++ca) {            // ca = c8 ^ ea (A-quad, literal)
    const int qa = ca << 2;                   // compile-time -> ds offset imm
    const int qb = (ca ^ eab) << 2;           // single runtime XOR
    v2f a01[4], a23[4], b01[4], b23[4];
#pragma unroll
    for (int i = 0; i < 4; ++i) {
      float4 av = *(const float4*)(sAr0 + i * 32 + qa);
      a01[i] = (v2f){av.x, av.y}; a23[i] = (v2f){av.z, av.w};
    }
#pragma unroll
    for (int j = 0; j < 4; ++j) {
      float4 bv = *(const float4*)(&sB[(s4 + j) * 32 + qb]);
      b01[j] = (v2f){bv.x, bv.y}; b23[j] = (v2f){bv.z, bv.w};
    }
#pragma unroll
    for (int i = 0; i < 4; ++i)
#pragma unroll
      for (int j = 0; j < 4; ++j) {
        acc2[i][j] = __builtin_elementwise_fma(a01[i], b01[j], acc2[i][j]);
        acc2[i][j] = __builtin_elementwise_fma(a23[i], b23[j], acc2[i][j]);
      }
  }

  // ---- h1 ready ----
  asm volatile("s_waitcnt vmcnt(0)" ::: "memory");
  __builtin_amdgcn_s_barrier();
  asm volatile("" ::: "memory");

#pragma unroll
  for (int ca = 0; ca < 8; ++ca) {
    const int qa = ca << 2;
    const int qb = (ca ^ eab) << 2;
    v2f a01[4], a23[4], b01[4], b23[4];
#pragma unroll
    for (int i = 0; i < 4; ++i) {
      float4 av = *(const float4*)(sAr1 + i * 32 + qa);
      a01[i] = (v2f){av.x, av.y}; a23[i] = (v2f){av.z, av.w};
    }
#pragma unroll
    for (int j = 0; j < 4; ++j) {
      float4 bv = *(const float4*)(&sB[2048 + (s4 + j) * 32 + qb]);
      b01[j] = (v2f){bv.x, bv.y}; b23[j] = (v2f){bv.z, bv.w};
    }
#pragma unroll
    for (int i = 0; i < 4; ++i)
#pragma unroll
      for (int j = 0; j < 4; ++j) {
        acc2[i][j] = __builtin_elementwise_fma(a01[i], b01[j], acc2[i][j]);
        acc2[i][j] = __builtin_elementwise_fma(a23[i], b23[j], acc2[i][j]);
      }
  }

  // ---- fold packed pairs to scalar ----
  float acc[4][4];
#pragma unroll
  for (int i = 0; i < 4; ++i)
#pragma unroll
    for (int j = 0; j < 4; ++j) acc[i][j] = acc2[i][j].x + acc2[i][j].y;

  // ---- softmax stats, unshifted: e = exp(sim/64); heat = e^2 * rinv * cinv ----
  float rinv[4];
#pragma unroll
  for (int i = 0; i < 4; ++i) {
    float rs = 0.0f;
#pragma unroll
    for (int j = 0; j < 4; ++j) { acc[i][j] = __expf(acc[i][j] * 0.015625f); rs += acc[i][j]; }
#pragma unroll
    for (int off = 1; off <= 8; off <<= 1) rs += __shfl_xor(rs, off);
    rinv[i] = 1.0f / rs;
  }
  {
    float cps[4];
#pragma unroll
    for (int j = 0; j < 4; ++j) {
      float cs = acc[0][j] + acc[1][j] + acc[2][j] + acc[3][j];
      cs += __shfl_xor(cs, 16);
      cs += __shfl_xor(cs, 32);
      cps[j] = cs;
    }
    if (lane < 16) *(float4*)(&colps[wave][s4]) = make_float4(cps[0], cps[1], cps[2], cps[3]);
  }
  asm volatile("s_waitcnt lgkmcnt(0)" ::: "memory");
  __builtin_amdgcn_s_barrier();
  asm volatile("" ::: "memory");

  float cinv[4];
  {
    float4 q0 = *(const float4*)(&colps[0][s4]);
    float4 q1 = *(const float4*)(&colps[1][s4]);
    float4 q2 = *(const float4*)(&colps[2][s4]);
    float4 q3 = *(const float4*)(&colps[3][s4]);
    cinv[0] = 1.0f / (q0.x + q1.x + q2.x + q3.x);
    cinv[1] = 1.0f / (q0.y + q1.y + q2.y + q3.y);
    cinv[2] = 1.0f / (q0.z + q1.z + q2.z + q3.z);
    cinv[3] = 1.0f / (q0.w + q1.w + q2.w + q3.w);
  }

  // ---- heatmap write + per-wave argmax; waves exit independently ----
  float best = -1.0f; int bidx = 0;
  float* outh = out + (size_t)m * 4096;
#pragma unroll
  for (int i = 0; i < 4; ++i) {
    float ri = rinv[i];
    float4 h;
    h.x = acc[i][0] * acc[i][0] * ri * cinv[0];
    h.y = acc[i][1] * acc[i][1] * ri * cinv[1];
    h.z = acc[i][2] * acc[i][2] * ri * cinv[2];
    h.w = acc[i][3] * acc[i][3] * ri * cinv[3];
    int base = (l4 + i) * 64 + s4;
    *(float4*)(outh + base) = h;
    if (h.x > best) { best = h.x; bidx = base; }
    if (h.y > best) { best = h.y; bidx = base + 1; }
    if (h.z > best) { best = h.z; bidx = base + 2; }
    if (h.w > best) { best = h.w; bidx = base + 3; }
  }
#pragma unroll
  for (int off = 32; off; off >>= 1) {
    float ov = __shfl_xor(best, off);
    int   oi = __shfl_xor(bidx, off);
    if (ov > best || (ov == best && oi < bidx)) { best = ov; bidx = oi; }
  }
  if (lane == 0) {
    uint2 pk;
    pk.x = __float_as_uint(best);
    pk.y = (unsigned)bidx;
    *((uint2*)ws + (size_t)m * 4 + wave) = pk;
  }
}

// ---------------- K2: argmax finalize + scalars + reg refinement ----------------
__global__ __launch_bounds__(256, 8) void fm_reg_kernel(
    const float* __restrict__ feat0, const float* __restrict__ feat1,
    float* __restrict__ out, const unsigned int* __restrict__ ws, int M)
{
  const int lane = threadIdx.x & 63;
  const int mw   = blockIdx.x * 4 + (threadIdx.x >> 6);
  if (mw >= M) return;

  float* const oS = out + (size_t)M * 4096;

  // 4-way reduce of per-wave argmax partials (all lanes redundantly)
  const uint2* wsp = (const uint2*)ws + (size_t)mw * 4;
  float fbv = -1.0f; int fbi = 0;
#pragma unroll
  for (int w = 0; w < 4; ++w) {
    uint2 pk = wsp[w];
    float ov = __uint_as_float(pk.x);
    int   oi = (int)pk.y;
    if (ov > fbv || (ov == fbv && oi < fbi)) { fbv = ov; fbi = oi; }
  }
  const int i0 = fbi >> 6, i1 = fbi & 63;

  if (lane == 0) {
    oS[mw]         = (float)i0;                       // idxes0
    oS[M + mw]     = (float)i1;                       // idxes1
    oS[2 * M + 2 * mw + 0] = (float)(i0 & 7) - 3.5f;  // biases0.x
    oS[2 * M + 2 * mw + 1] = (float)(i0 >> 3) - 3.5f; // biases0.y
    oS[4 * M + 2 * mw + 0] = (float)(i1 & 7) - 3.5f;  // biases1.x
    oS[4 * M + 2 * mw + 1] = (float)(i1 >> 3) - 3.5f; // biases1.y
  }

  const float* f0p = feat0 + (size_t)mw * 8192;
  const float* f1p = feat1 + (size_t)mw * 12800;

  const float rf0 = f0p[i0 * 128 + 64 + lane];
  const int r0 = i1 >> 3, c0 = i1 & 7;

  float p[9];
#pragma unroll
  for (int a = 0; a < 3; ++a)
#pragma unroll
    for (int b = 0; b < 3; ++b)
      p[a * 3 + b] = f1p[((r0 + a) * 10 + (c0 + b)) * 128 + 64 + lane] * rf0;

#pragma unroll
  for (int r = 0; r < 9; ++r)
#pragma unroll
    for (int off = 32; off; off >>= 1) p[r] += __shfl_xor(p[r], off);

  if (lane == 0) {
    float mx = p[0];
#pragma unroll
    for (int r = 1; r < 9; ++r) mx = fmaxf(mx, p[r]);
    float e[9], ssum = 0.0f;
#pragma unroll
    for (int r = 0; r < 9; ++r) { e[r] = __expf((p[r] - mx) * 0.125f); ssum += e[r]; }
    float inv = 1.0f / ssum, bx = 0.0f, by = 0.0f;
#pragma unroll
    for (int r = 0; r < 9; ++r) {
      float w = e[r] * inv;
      bx += w * (float)((r % 3) - 1);
      by += w * (float)((r / 3) - 1);
    }
    oS[6 * M + 2 * mw + 0] = bx;
    oS[6 * M + 2 * mw + 1] = by;
  }
}

extern "C" void kernel_launch(void* const* d_in, const int* in_sizes, int n_in,
                              void* d_out, int out_size, void* d_ws, size_t ws_size,
                              hipStream_t stream) {
  const float* f0 = (const float*)d_in[0];
  const float* f1 = (const float*)d_in[1];
  float* out = (float*)d_out;
  unsigned int* ws = (unsigned int*)d_ws;
  int M = in_sizes[0] / 8192;  // 64*128 per row
  fm_main_kernel<<<dim3(M), dim3(256), 0, stream>>>(f0, f1, out, ws, M);
  fm_reg_kernel<<<dim3((M + 3) / 4), dim3(256), 0, stream>>>(f0, f1, out, ws, M);
}

// Round 19
// 218.596 us; speedup vs baseline: 1.0533x; 1.0533x over previous
//
#include <hip/hip_runtime.h>

typedef float v2f __attribute__((ext_vector_type(2)));

// Async global->LDS, 16B per lane. Dest = wave-uniform base + lane*16.
__device__ __forceinline__ void gload_lds16(const float* g, float* l) {
  __builtin_amdgcn_global_load_lds(
      (const __attribute__((address_space(1))) unsigned int*)g,
      (__attribute__((address_space(3))) unsigned int*)l, 16, 0, 0);
}

// ---------------- K1: sim + dual softmax + heatmap + per-wave argmax ----------------
// Champion (219.7 us, R17): one m per block, LDS [half][row][32], source-side
// XOR swizzle e(p)=(p>>2)&7, counted-vmcnt h0/h1 split, packed v_pk_fma_f32
// accumulation, in-register softmax, per-wave argmax spilled to ws (finalized
// in K2). NOTE (R18 lesson): BOTH read-side XORs (ea for A, eb for B) are
// load-bearing for LDS bank spreading -- rows are 128 B apart (= 32-bank
// period), so a lane-uniform quad offset causes 4-way (A) / 16-way (B)
// conflicts. Do not "optimize" them into literals.
__global__ __launch_bounds__(256, 4) void fm_main_kernel(
    const float* __restrict__ feat0, const float* __restrict__ feat1,
    float* __restrict__ out, unsigned int* __restrict__ ws, int M)
{
  const int t    = threadIdx.x;
  const int lane = t & 63;
  const int wave = t >> 6;

  __shared__ __align__(16) float sA[4096];      // [2][64][32] halves of cls_f0
  __shared__ __align__(16) float sB[4096];      // [2][64][32] halves of cls_f1 inner
  __shared__ __align__(16) float colps[4][64];  // per-wave col-sum partials

  const int m = blockIdx.x;
  const float* f0m = feat0 + (size_t)m * 8192;   // 64*128
  const float* f1m = feat1 + (size_t)m * 12800;  // 100*128

  // ---- stage: 8 gload_lds per wave, h0 (c<32) first, then h1 ----
  const int pr = lane >> 3;   // row within 8-row chunk
  const int q  = lane & 7;    // slot quad within half
#pragma unroll
  for (int h = 0; h < 2; ++h) {
#pragma unroll
    for (int k = 0; k < 2; ++k) {
      const int p0 = wave * 16 + k * 8;
      const int p  = p0 + pr;
      const int gq = q ^ ((p >> 2) & 7);          // source-side swizzle
      gload_lds16(f0m + p * 128 + h * 32 + gq * 4, &sA[h * 2048 + p0 * 32]);
      const int r = ((p >> 3) + 1) * 10 + (p & 7) + 1;  // inner 8x8 of 10x10
      gload_lds16(f1m + r * 128 + h * 32 + gq * 4, &sB[h * 2048 + p0 * 32]);
    }
  }

  // address setup under the load shadow
  const int st = t & 15, lt = t >> 4;
  const int s4 = st << 2, l4 = lt << 2;
  const int ea = lt & 7, eb = st & 7;   // read-side XOR (= e(p) of owned rows)

  v2f acc2[4][4];
#pragma unroll
  for (int i = 0; i < 4; ++i)
#pragma unroll
    for (int j = 0; j < 4; ++j) acc2[i][j] = (v2f){0.0f, 0.0f};

  // ---- h0 ready (oldest 4 loads), all waves -> compute c<32 while h1 drains ----
  asm volatile("s_waitcnt vmcnt(4)" ::: "memory");
  __builtin_amdgcn_s_barrier();
  asm volatile("" ::: "memory");

#pragma unroll
  for (int c8 = 0; c8 < 8; ++c8) {
    const int qa = (c8 ^ ea) << 2, qb = (c8 ^ eb) << 2;
    v2f a01[4], a23[4], b01[4], b23[4];
#pragma unroll
    for (int i = 0; i < 4; ++i) {
      float4 av = *(const float4*)(&sA[(l4 + i) * 32 + qa]);
      a01[i] = (v2f){av.x, av.y}; a23[i] = (v2f){av.z, av.w};
    }
#pragma unroll
    for (int j = 0; j < 4; ++j) {
      float4 bv = *(const float4*)(&sB[(s4 + j) * 32 + qb]);
      b01[j] = (v2f){bv.x, bv.y}; b23[j] = (v2f){bv.z, bv.w};
    }
#pragma unroll
    for (int i = 0; i < 4; ++i)
#pragma unroll
      for (int j = 0; j < 4; ++j) {
        acc2[i][j] = __builtin_elementwise_fma(a01[i], b01[j], acc2[i][j]);
        acc2[i][j] = __builtin_elementwise_fma(a23[i], b23[j], acc2[i][j]);
      }
  }

  // ---- h1 ready ----
  asm volatile("s_waitcnt vmcnt(0)" ::: "memory");
  __builtin_amdgcn_s_barrier();
  asm volatile("" ::: "memory");

#pragma unroll
  for (int c8 = 0; c8 < 8; ++c8) {
    const int qa = (c8 ^ ea) << 2, qb = (c8 ^ eb) << 2;
    v2f a01[4], a23[4], b01[4], b23[4];
#pragma unroll
    for (int i = 0; i < 4; ++i) {
      float4 av = *(const float4*)(&sA[2048 + (l4 + i) * 32 + qa]);
      a01[i] = (v2f){av.x, av.y}; a23[i] = (v2f){av.z, av.w};
    }
#pragma unroll
    for (int j = 0; j < 4; ++j) {
      float4 bv = *(const float4*)(&sB[2048 + (s4 + j) * 32 + qb]);
      b01[j] = (v2f){bv.x, bv.y}; b23[j] = (v2f){bv.z, bv.w};
    }
#pragma unroll
    for (int i = 0; i < 4; ++i)
#pragma unroll
      for (int j = 0; j < 4; ++j) {
        acc2[i][j] = __builtin_elementwise_fma(a01[i], b01[j], acc2[i][j]);
        acc2[i][j] = __builtin_elementwise_fma(a23[i], b23[j], acc2[i][j]);
      }
  }

  // ---- fold packed pairs to scalar ----
  float acc[4][4];
#pragma unroll
  for (int i = 0; i < 4; ++i)
#pragma unroll
    for (int j = 0; j < 4; ++j) acc[i][j] = acc2[i][j].x + acc2[i][j].y;

  // ---- softmax stats, unshifted: e = exp(sim/64); heat = e^2 * rinv * cinv ----
  float rinv[4];
#pragma unroll
  for (int i = 0; i < 4; ++i) {
    float rs = 0.0f;
#pragma unroll
    for (int j = 0; j < 4; ++j) { acc[i][j] = __expf(acc[i][j] * 0.015625f); rs += acc[i][j]; }
#pragma unroll
    for (int off = 1; off <= 8; off <<= 1) rs += __shfl_xor(rs, off);
    rinv[i] = 1.0f / rs;
  }
  {
    float cps[4];
#pragma unroll
    for (int j = 0; j < 4; ++j) {
      float cs = acc[0][j] + acc[1][j] + acc[2][j] + acc[3][j];
      cs += __shfl_xor(cs, 16);
      cs += __shfl_xor(cs, 32);
      cps[j] = cs;
    }
    if (lane < 16) *(float4*)(&colps[wave][s4]) = make_float4(cps[0], cps[1], cps[2], cps[3]);
  }
  asm volatile("s_waitcnt lgkmcnt(0)" ::: "memory");
  __builtin_amdgcn_s_barrier();
  asm volatile("" ::: "memory");

  float cinv[4];
  {
    float4 q0 = *(const float4*)(&colps[0][s4]);
    float4 q1 = *(const float4*)(&colps[1][s4]);
    float4 q2 = *(const float4*)(&colps[2][s4]);
    float4 q3 = *(const float4*)(&colps[3][s4]);
    cinv[0] = 1.0f / (q0.x + q1.x + q2.x + q3.x);
    cinv[1] = 1.0f / (q0.y + q1.y + q2.y + q3.y);
    cinv[2] = 1.0f / (q0.z + q1.z + q2.z + q3.z);
    cinv[3] = 1.0f / (q0.w + q1.w + q2.w + q3.w);
  }

  // ---- heatmap write + per-wave argmax; waves exit independently ----
  float best = -1.0f; int bidx = 0;
  float* outh = out + (size_t)m * 4096;
#pragma unroll
  for (int i = 0; i < 4; ++i) {
    float ri = rinv[i];
    float4 h;
    h.x = acc[i][0] * acc[i][0] * ri * cinv[0];
    h.y = acc[i][1] * acc[i][1] * ri * cinv[1];
    h.z = acc[i][2] * acc[i][2] * ri * cinv[2];
    h.w = acc[i][3] * acc[i][3] * ri * cinv[3];
    int base = (l4 + i) * 64 + s4;
    *(float4*)(outh + base) = h;
    if (h.x > best) { best = h.x; bidx = base; }
    if (h.y > best) { best = h.y; bidx = base + 1; }
    if (h.z > best) { best = h.z; bidx = base + 2; }
    if (h.w > best) { best = h.w; bidx = base + 3; }
  }
#pragma unroll
  for (int off = 32; off; off >>= 1) {
    float ov = __shfl_xor(best, off);
    int   oi = __shfl_xor(bidx, off);
    if (ov > best || (ov == best && oi < bidx)) { best = ov; bidx = oi; }
  }
  if (lane == 0) {
    uint2 pk;
    pk.x = __float_as_uint(best);
    pk.y = (unsigned)bidx;
    *((uint2*)ws + (size_t)m * 4 + wave) = pk;
  }
}

// ---------------- K2: argmax finalize + scalars + reg refinement ----------------
__global__ __launch_bounds__(256, 8) void fm_reg_kernel(
    const float* __restrict__ feat0, const float* __restrict__ feat1,
    float* __restrict__ out, const unsigned int* __restrict__ ws, int M)
{
  const int lane = threadIdx.x & 63;
  const int mw   = blockIdx.x * 4 + (threadIdx.x >> 6);
  if (mw >= M) return;

  float* const oS = out + (size_t)M * 4096;

  // 4-way reduce of per-wave argmax partials (all lanes redundantly)
  const uint2* wsp = (const uint2*)ws + (size_t)mw * 4;
  float fbv = -1.0f; int fbi = 0;
#pragma unroll
  for (int w = 0; w < 4; ++w) {
    uint2 pk = wsp[w];
    float ov = __uint_as_float(pk.x);
    int   oi = (int)pk.y;
    if (ov > fbv || (ov == fbv && oi < fbi)) { fbv = ov; fbi = oi; }
  }
  const int i0 = fbi >> 6, i1 = fbi & 63;

  if (lane == 0) {
    oS[mw]         = (float)i0;                       // idxes0
    oS[M + mw]     = (float)i1;                       // idxes1
    oS[2 * M + 2 * mw + 0] = (float)(i0 & 7) - 3.5f;  // biases0.x
    oS[2 * M + 2 * mw + 1] = (float)(i0 >> 3) - 3.5f; // biases0.y
    oS[4 * M + 2 * mw + 0] = (float)(i1 & 7) - 3.5f;  // biases1.x
    oS[4 * M + 2 * mw + 1] = (float)(i1 >> 3) - 3.5f; // biases1.y
  }

  const float* f0p = feat0 + (size_t)mw * 8192;
  const float* f1p = feat1 + (size_t)mw * 12800;

  const float rf0 = f0p[i0 * 128 + 64 + lane];
  const int r0 = i1 >> 3, c0 = i1 & 7;

  float p[9];
#pragma unroll
  for (int a = 0; a < 3; ++a)
#pragma unroll
    for (int b = 0; b < 3; ++b)
      p[a * 3 + b] = f1p[((r0 + a) * 10 + (c0 + b)) * 128 + 64 + lane] * rf0;

#pragma unroll
  for (int r = 0; r < 9; ++r)
#pragma unroll
    for (int off = 32; off; off >>= 1) p[r] += __shfl_xor(p[r], off);

  if (lane == 0) {
    float mx = p[0];
#pragma unroll
    for (int r = 1; r < 9; ++r) mx = fmaxf(mx, p[r]);
    float e[9], ssum = 0.0f;
#pragma unroll
    for (int r = 0; r < 9; ++r) { e[r] = __expf((p[r] - mx) * 0.125f); ssum += e[r]; }
    float inv = 1.0f / ssum, bx = 0.0f, by = 0.0f;
#pragma unroll
    for (int r = 0; r < 9; ++r) {
      float w = e[r] * inv;
      bx += w * (float)((r % 3) - 1);
      by += w * (float)((r / 3) - 1);
    }
    oS[6 * M + 2 * mw + 0] = bx;
    oS[6 * M + 2 * mw + 1] = by;
  }
}

extern "C" void kernel_launch(void* const* d_in, const int* in_sizes, int n_in,
                              void* d_out, int out_size, void* d_ws, size_t ws_size,
                              hipStream_t stream) {
  const float* f0 = (const float*)d_in[0];
  const float* f1 = (const float*)d_in[1];
  float* out = (float*)d_out;
  unsigned int* ws = (unsigned int*)d_ws;
  int M = in_sizes[0] / 8192;  // 64*128 per row
  fm_main_kernel<<<dim3(M), dim3(256), 0, stream>>>(f0, f1, out, ws, M);
  fm_reg_kernel<<<dim3((M + 3) / 4), dim3(256), 0, stream>>>(f0, f1, out, ws, M);
}